// Round 1
// baseline (97.611 us; speedup 1.0000x reference)
//
#include <hip/hip_runtime.h>
#include <math.h>

#define EPS   1e-6f
#define BB    256
#define NNEG  1000
#define HH    3
#define DD    128
#define NCN   250   // neg_im2cluster values are in [0, min(NUM_CLUSTER)) = [0,250)

// workspace float offsets
#define OFF_CENT_T   0          // 3*128*250 = 96000 floats
#define OFF_SE_N     96000      // 256*3*128 = 98304
#define OFF_POS_LOSS 194304     // 256
#define OFF_SIM      194560     // 256*3*250 = 192000
#define OFF_POS_LAB  386560     // 768 ints
// total ~387328 floats = ~1.55 MB of d_ws

// K1: normalize centroid rows 0..249 of each hierarchy, store transposed [h][d][c]
__global__ void k1_cent_prep(const float* __restrict__ c0,
                             const float* __restrict__ c1,
                             const float* __restrict__ c2,
                             float* __restrict__ centT) {
    int wid  = blockIdx.x * 4 + (threadIdx.x >> 6);
    int lane = threadIdx.x & 63;
    if (wid >= HH * NCN) return;
    int h = wid / NCN;
    int c = wid - h * NCN;
    const float* cp = (h == 0) ? c0 : (h == 1) ? c1 : c2;
    const float2 v = *(const float2*)(cp + (size_t)c * DD + lane * 2);
    float ss = v.x * v.x + v.y * v.y;
    #pragma unroll
    for (int off = 32; off; off >>= 1) ss += __shfl_xor(ss, off);
    float inv = 1.0f / fmaxf(sqrtf(ss), 1e-12f);
    float* base = centT + h * (DD * NCN);
    base[(lane * 2)     * NCN + c] = v.x * inv;
    base[(lane * 2 + 1) * NCN + c] = v.y * inv;
}

// K2: per-b: normalize se rows (store), positive-path loss + labels (inline centroid norm)
__global__ void k2_se_pos(const float* __restrict__ se,
                          const float* __restrict__ c0,
                          const float* __restrict__ c1,
                          const float* __restrict__ c2,
                          const int* __restrict__ i2c0,
                          const int* __restrict__ i2c1,
                          const int* __restrict__ i2c2,
                          const int* __restrict__ index,
                          float* __restrict__ se_n,
                          float* __restrict__ pos_loss,
                          int* __restrict__ pos_lab) {
    int b    = blockIdx.x;
    int h    = threadIdx.x >> 6;   // 3 waves, one per hierarchy
    int lane = threadIdx.x & 63;
    __shared__ float ph_s[HH];

    // normalize this sample's h-th embedding row
    const float2 s = *(const float2*)(se + (size_t)b * (HH * DD) + h * DD + lane * 2);
    float ss = s.x * s.x + s.y * s.y;
    #pragma unroll
    for (int off = 32; off; off >>= 1) ss += __shfl_xor(ss, off);
    float inv = 1.0f / fmaxf(sqrtf(ss), 1e-12f);
    float2 sn = make_float2(s.x * inv, s.y * inv);
    float* sp = se_n + ((size_t)b * HH + h) * DD + lane * 2;
    sp[0] = sn.x; sp[1] = sn.y;

    // positive centroid: gather + fused dot/sumsq in one pass
    int idx  = index[b];
    const int*   ip = (h == 0) ? i2c0 : (h == 1) ? i2c1 : i2c2;
    const float* cp = (h == 0) ? c0   : (h == 1) ? c1   : c2;
    int cidx = ip[idx];
    const float2 cv = *(const float2*)(cp + (size_t)cidx * DD + lane * 2);
    float dot = sn.x * cv.x + sn.y * cv.y;
    float csq = cv.x * cv.x + cv.y * cv.y;
    #pragma unroll
    for (int off = 32; off; off >>= 1) {
        dot += __shfl_xor(dot, off);
        csq += __shfl_xor(csq, off);
    }
    if (lane == 0) {
        float invc = 1.0f / fmaxf(sqrtf(csq), 1e-12f);
        ph_s[h] = (dot * invc + 1.0f) * 0.5f;
        pos_lab[b * HH + h] = cidx;
    }
    __syncthreads();
    if (threadIdx.x == 0)
        pos_loss[b] = -logf(ph_s[0] * ph_s[1] * ph_s[2] + EPS);
}

// K3: sim[b,h,c] path-factor table = (dot(se_n[b,h], cent_n[h][c]) + 1) * 0.5
__global__ void k3_sim(const float* __restrict__ se_n,
                       const float* __restrict__ centT,
                       float* __restrict__ sim) {
    int b = blockIdx.x, h = blockIdx.y;
    int tid = threadIdx.x;
    __shared__ float sse[DD];
    if (tid < DD) sse[tid] = se_n[((size_t)b * HH + h) * DD + tid];
    __syncthreads();
    if (tid < NCN) {
        const float* ct = centT + h * (DD * NCN) + tid;
        float acc = 0.0f;
        #pragma unroll 8
        for (int d = 0; d < DD; ++d) acc = fmaf(sse[d], ct[d * NCN], acc);
        sim[((size_t)b * HH + h) * NCN + tid] = (acc + 1.0f) * 0.5f;
    }
}

// K4: negative-path loss via LDS sim lookups; block reduce; atomic into scalar out
__global__ void k4_neg(const int* __restrict__ negc,
                       const float* __restrict__ sim,
                       const int* __restrict__ pos_lab,
                       const float* __restrict__ pos_loss,
                       float* __restrict__ out) {
    int b = blockIdx.x, tid = threadIdx.x;
    __shared__ float ssim[HH * NCN];
    __shared__ int   slab[HH];
    __shared__ float wL[4], wT[4];
    for (int i = tid; i < HH * NCN; i += 256) ssim[i] = sim[(size_t)b * HH * NCN + i];
    if (tid < HH) slab[tid] = pos_lab[b * HH + tid];
    __syncthreads();
    int l0 = slab[0], l1 = slab[1], l2 = slab[2];
    float accL = 0.0f, accT = 0.0f;
    for (int n = tid; n < NNEG; n += 256) {
        const int* q = negc + ((size_t)b * NNEG + n) * HH;
        int i0 = q[0], i1 = q[1], i2 = q[2];
        float p = ssim[i0] * ssim[NCN + i1] * ssim[2 * NCN + i2];
        if (i0 != l0 || i1 != l1 || i2 != l2) {
            accL -= logf(1.0f - p + EPS);
            accT += 1.0f;
        }
    }
    #pragma unroll
    for (int off = 32; off; off >>= 1) {
        accL += __shfl_xor(accL, off);
        accT += __shfl_xor(accT, off);
    }
    int wid = tid >> 6, lane = tid & 63;
    if (lane == 0) { wL[wid] = accL; wT[wid] = accT; }
    __syncthreads();
    if (tid == 0) {
        float L = wL[0] + wL[1] + wL[2] + wL[3];
        float T = wT[0] + wT[1] + wT[2] + wT[3];
        float nb = L / (T + EPS);
        atomicAdd(out, (pos_loss[b] + nb) * (1.0f / (2.0f * BB)));
    }
}

extern "C" void kernel_launch(void* const* d_in, const int* in_sizes, int n_in,
                              void* d_out, int out_size, void* d_ws, size_t ws_size,
                              hipStream_t stream) {
    const float* se    = (const float*)d_in[0];
    const float* c0    = (const float*)d_in[1];
    const float* c1    = (const float*)d_in[2];
    const float* c2    = (const float*)d_in[3];
    const int*   i2c0  = (const int*)d_in[4];
    const int*   i2c1  = (const int*)d_in[5];
    const int*   i2c2  = (const int*)d_in[6];
    const int*   index = (const int*)d_in[7];
    const int*   negc  = (const int*)d_in[8];

    float* ws       = (float*)d_ws;
    float* centT    = ws + OFF_CENT_T;
    float* se_n     = ws + OFF_SE_N;
    float* pos_loss = ws + OFF_POS_LOSS;
    float* sim      = ws + OFF_SIM;
    int*   pos_lab  = (int*)(ws + OFF_POS_LAB);
    float* out      = (float*)d_out;

    hipMemsetAsync(out, 0, sizeof(float), stream);

    // K1: 750 rows, 1 wave per row, 4 waves/block
    hipLaunchKernelGGL(k1_cent_prep, dim3((HH * NCN + 3) / 4), dim3(256), 0, stream,
                       c0, c1, c2, centT);
    // K2: one block per b, 3 waves (one per hierarchy)
    hipLaunchKernelGGL(k2_se_pos, dim3(BB), dim3(192), 0, stream,
                       se, c0, c1, c2, i2c0, i2c1, i2c2, index, se_n, pos_loss, pos_lab);
    // K3: one block per (b,h)
    hipLaunchKernelGGL(k3_sim, dim3(BB, HH), dim3(256), 0, stream, se_n, centT, sim);
    // K4: one block per b
    hipLaunchKernelGGL(k4_neg, dim3(BB), dim3(256), 0, stream,
                       negc, sim, pos_lab, pos_loss, out);
}